// Round 12
// baseline (168.656 us; speedup 1.0000x reference)
//
#include <hip/hip_runtime.h>
#include <hip/hip_fp16.h>

// EdgeNetwork: SINGLE persistent kernel (prep -> barrier -> MFMA+pk-atomic
// scatter -> barrier -> finalize), tree-release grid barrier.
//
// Journal:
// R0: hipLaunchCooperativeKernel silently no-ops under graph capture. NEVER.
// R1: occupancy x2 -> neutral. Not latency-bound.
// R3: dst-sort cut touches 3x but +3 dispatches (~8-10us each) -> net loss.
// R4: launch_bounds(256,4) -> VGPR 80->64 scratch spills. Keep (256,3).
// R5: pk_add_f16 halved atomic DWORDS, time unchanged -> wall = atomic
//     SECTOR-TOUCHES at the coherence point (~14.5G/s). 400k = ~28us floor.
// R6: full-row waves, 1 pk-instr per edge-row: 800k->400k touches. 128.2us.
// R8: megakernel 285us: all-thread RMW spin flood (partially wrong theory).
// R9: leader/load-poll barrier -> 260us. Spin-traffic theory falsified.
// R10: 3-dispatch minimal prep = 124.1us BEST. Gaps+restores ~35us of it.
// R11: all-thread fences were the real R8/R9 cost: per-block single fence
//     -> 260->100us (-160, confirmed). Residual ~50us localized: single
//     `go` dword = 767 pollers serializing on ONE sector at the coherence
//     point (~10-25us/barrier) + smeared phase-B start.
// R12 (this, FINAL megakernel attempt): tree-release. Leader writes a
//     per-block release flag at 64B stride (12 agent-scope exchanges across
//     64 lanes -- RMWs, NOT plain stores: a relaxed store would strand in
//     XCD0's non-coherent L2 and deadlock). Each block polls its OWN sector.
//     KILL RULE: edge_all > 70us or total > 124 -> megakernel dead forever,
//     revert to R10.

typedef _Float16 half8 __attribute__((ext_vector_type(8)));
typedef _Float16 half4t __attribute__((ext_vector_type(4)));
typedef float float4v __attribute__((ext_vector_type(4)));

constexpr int NA = 100000;
constexpr int E  = 400000;
constexpr int GRP   = E / 16;          // 25000 16-edge groups
constexpr int NBLK  = 768;             // exactly co-resident (proven R8-R11)
constexpr int NWAVE = NBLK * 4;        // 3072 persistent waves
constexpr int NTHR  = NBLK * 256;      // 196608 threads

// ---- workspace layout (bytes) ----
constexpr size_t OFF_ATOMH = 0;                    // f16[NA*32]  6.4 MB
constexpr size_t OFF_ACC   = (size_t)NA * 32 * 2;  // f16[NA*32]  6.4 MB
constexpr size_t OFF_BARA  = OFF_ACC + (size_t)NA * 32 * 2;   // u32[768]
constexpr size_t OFF_BARB  = OFF_BARA + 4096;                 // u32[768]
constexpr size_t OFF_RELA  = OFF_BARB + 4096;   // u32[768*16] 48KB, 64B stride
constexpr size_t OFF_RELB  = OFF_RELA + 49152;  // u32[768*16] 48KB

constexpr unsigned MAGIC_A = 0x9E3779B1u;   // not byte-replicated (poison-safe)
constexpr unsigned MAGIC_B = 0x85EBCA77u;

constexpr int NZ4 = NA * 32 / 4;       // accum zero, half4t units (800k)
constexpr int NA4 = NA * 32 / 4;       // atom convert, float4 units (800k)
constexpr int PHASEA_TOT = NZ4 + NA4;  // 1.6M

constexpr int WSTRIDE = 80;            // LDS bytes per W n-row

static __device__ inline half8 splat8(_Float16 v) {
  half8 r = {v, v, v, v, v, v, v, v};
  return r;
}

// Device-wide barrier, exactly-resident NBLK blocks. Arrival: one release-
// exchange per block (its wbl2 flushes that XCD's dirty lines). Leader wave
// load-polls the 768 arrival flags, then broadcasts via ONE release flag PER
// BLOCK at 64B stride (agent-scope RMWs -> land at the coherence point; no
// shared hot sector). Each block polls its own flag. One acquire fence
// (buffer_inv) per block on exit.
static __device__ inline void grid_barrier(unsigned* flags, unsigned* rel,
                                           unsigned magic) {
  __syncthreads();
  if (threadIdx.x == 0) {
    (void)__hip_atomic_exchange(flags + blockIdx.x, magic, __ATOMIC_RELEASE,
                                __HIP_MEMORY_SCOPE_AGENT);
  }
  if (blockIdx.x == 0) {
    if (threadIdx.x < 64) {                      // leader wave polls 768 flags
      for (;;) {
        int ok = 1;
        #pragma unroll
        for (int r = 0; r < 12; ++r) {           // 64*12 = 768
          unsigned v = __hip_atomic_load(flags + threadIdx.x + r * 64,
                                         __ATOMIC_RELAXED,
                                         __HIP_MEMORY_SCOPE_AGENT);
          ok &= (v == magic);
        }
        if (__all(ok)) break;
        __builtin_amdgcn_s_sleep(8);
      }
      // Tree release: per-block flag, 64B apart, agent-scope exchange (RMW).
      #pragma unroll
      for (int r = 0; r < 12; ++r) {
        const int b = threadIdx.x + r * 64;
        (void)__hip_atomic_exchange(rel + b * 16, magic, __ATOMIC_RELAXED,
                                    __HIP_MEMORY_SCOPE_AGENT);
      }
    }
  } else if (threadIdx.x == 0) {
    while (__hip_atomic_load(rel + blockIdx.x * 16, __ATOMIC_RELAXED,
                             __HIP_MEMORY_SCOPE_AGENT) != magic)
      __builtin_amdgcn_s_sleep(4);
  }
  if (threadIdx.x == 0)
    __builtin_amdgcn_fence(__ATOMIC_ACQUIRE, "agent");  // one buffer_inv/block
  __syncthreads();
}

__global__ __launch_bounds__(256, 3)
void edge_all(const float* __restrict__ atom,
              const float* __restrict__ bondf,
              const int* __restrict__ pairs,
              const float* __restrict__ Kmat,
              const float* __restrict__ bias,
              float* __restrict__ out,
              _Float16* __restrict__ atomh,
              _Float16* __restrict__ accum,
              unsigned* __restrict__ barA,
              unsigned* __restrict__ barB,
              unsigned* __restrict__ relA,
              unsigned* __restrict__ relB)
{
  __shared__ __attribute__((aligned(16))) char wl[17 * 16 * WSTRIDE];

  const int tid  = threadIdx.x;
  const int lane = tid & 63;
  const int wid  = blockIdx.x * 4 + (tid >> 6);
  const int q    = lane >> 4;
  const int el   = lane & 15;
  const int j0   = q * 8;
  const int gid  = blockIdx.x * 256 + tid;

  // LDS: h1 half of W (cols 16..31) + bias row, f16.
  for (int i4 = tid; i4 < 17 * 16 * 32 / 4; i4 += 256) {
    const int i   = i4 * 4;
    const int s   = i >> 9;
    const int r   = i & 511;
    const int n16 = r >> 5;
    const int j   = r & 31;
    const float* src = (s < 16) ? (Kmat + s * 1024 + (n16 + 16) * 32 + j)
                                : (bias + (n16 + 16) * 32 + j);
    float4 v = *(const float4*)src;
    half4t hh = { (_Float16)v.x, (_Float16)v.y, (_Float16)v.z, (_Float16)v.w };
    *(half4t*)(wl + (s * 16 + n16) * WSTRIDE + j * 2) = hh;
  }

  // h0 W-half (cols 0..15) register-resident (proven Wr layout).
  half8 Wr[17];
  #pragma unroll
  for (int s = 0; s < 17; ++s) {
    const float* src = (s < 16) ? (Kmat + s * 1024 + el * 32 + j0)
                                : (bias + el * 32 + j0);
    half8 w;
    #pragma unroll
    for (int j = 0; j < 8; ++j) w[j] = (_Float16)src[j];
    Wr[s] = w;
  }

  // ---- Phase A: zero f16 accum + convert atom f32->f16 (grid-stride). ----
  {
    half4t* acc4 = (half4t*)accum;
    half4t* atomh4 = (half4t*)atomh;
    const float4* atom4 = (const float4*)atom;
    for (int i = gid; i < PHASEA_TOT; i += NTHR) {
      if (i < NZ4) {
        half4t z = { (_Float16)0.f, (_Float16)0.f, (_Float16)0.f, (_Float16)0.f };
        acc4[i] = z;
      } else {
        const int k = i - NZ4;
        float4 v = atom4[k];
        half4t hh = { (_Float16)v.x, (_Float16)v.y, (_Float16)v.z, (_Float16)v.w };
        atomh4[k] = hh;
      }
    }
  }
  grid_barrier(barA, relA, MAGIC_A);   // also covers LDS fill (__syncthreads)

  // ---- Phase B: MFMA + one-pk-instruction-per-row scatter (R10 structure,
  //      bond streamed as f32 and converted at the splat). ----
  {
    const int2* pairs2 = (const int2*)pairs;
    const char* wb = wl + el * WSTRIDE + q * 16;   // h1 frag base (n = el+16)

    auto ldpv = [&](int g) -> int2 {
      const int gc = g < GRP ? g : GRP - 1;        // clamp: loads stay valid
      int2 v = make_int2(0, 0);
      if (lane < 16) v = pairs2[gc * 16 + lane];
      return v;
    };

    int2 pv0 = ldpv(wid);
    int2 pv1 = ldpv(wid + NWAVE);

    half8 nb_c; float4v c0_c, c1_c, c2_c, c3_c;
    {
      const int a = __shfl(pv0.y, el);
      nb_c = *(const half8*)(atomh + (size_t)a * 32 + j0);
      const float4v* br = (const float4v*)(bondf + (size_t)(wid * 16 + el) * 16);
      c0_c = br[0]; c1_c = br[1]; c2_c = br[2]; c3_c = br[3];
    }

    for (int g = wid; g < GRP; g += NWAVE) {
      const int gn = g + NWAVE;

      // Stage next group (loads in flight across this group's compute).
      half8 nb_n; float4v c0_n, c1_n, c2_n, c3_n;
      {
        const int a = __shfl(pv1.y, el);
        nb_n = *(const half8*)(atomh + (size_t)a * 32 + j0);
        const int gc = gn < GRP ? gn : GRP - 1;
        const float4v* br = (const float4v*)(bondf + (size_t)(gc * 16 + el) * 16);
        c0_n = br[0]; c1_n = br[1]; c2_n = br[2]; c3_n = br[3];
      }
      const int2 pv2 = ldpv(gn + NWAVE);

      // Opaque zero (SGPR) so loop-invariant LDS reads are not hoisted.
      int zz;
      asm volatile("s_mov_b32 %0, 0" : "=s"(zz));
      const char* wbz = wb + zz;

      float4v a0 = {0.f, 0.f, 0.f, 0.f};
      float4v a1 = {0.f, 0.f, 0.f, 0.f};
      #pragma unroll
      for (int s = 0; s < 16; ++s) {
        const float scf = (s < 4) ? c0_c[s] : (s < 8) ? c1_c[s - 4]
                         : (s < 12) ? c2_c[s - 8] : c3_c[s - 12];
        const half8 af = nb_c * splat8((_Float16)scf);
        const half8 w1 = *(const half8*)(wbz + s * 16 * WSTRIDE);
        a0 = __builtin_amdgcn_mfma_f32_16x16x32_f16(af, Wr[s], a0, 0, 0, 0);
        a1 = __builtin_amdgcn_mfma_f32_16x16x32_f16(af, w1,    a1, 0, 0, 0);
      }
      {
        const half8 w1 = *(const half8*)(wbz + 16 * 16 * WSTRIDE);
        a0 = __builtin_amdgcn_mfma_f32_16x16x32_f16(nb_c, Wr[16], a0, 0, 0, 0);
        a1 = __builtin_amdgcn_mfma_f32_16x16x32_f16(nb_c, w1,     a1, 0, 0, 0);
      }

      // Epilogue: one pk-atomic instruction per 4 edge-rows (full 64B row).
      const bool ev = !(el & 1);
      #pragma unroll
      for (int r = 0; r < 4; ++r) {
        const int   d  = __shfl(pv0.x, q * 4 + r);
        const float v0 = a0[r], v1 = a1[r];
        const float p0 = __shfl_xor(v0, 1);
        const float p1 = __shfl_xor(v1, 1);
        union { _Float16 f[2]; __half2 h; } u;
        u.f[0] = ev ? (_Float16)v0 : (_Float16)p1;
        u.f[1] = ev ? (_Float16)p0 : (_Float16)v1;
        const int col = ev ? el : (15 + el);
        unsafeAtomicAdd(reinterpret_cast<__half2*>(
                            accum + (size_t)d * 32 + col), u.h);
      }

      pv0 = pv1; pv1 = pv2;
      nb_c = nb_n;
      c0_c = c0_n; c1_c = c1_n; c2_c = c2_n; c3_c = c3_n;
    }
  }
  grid_barrier(barB, relB, MAGIC_B);

  // ---- Phase C: accum f16 -> out f32. Agent-scope atomic loads: bypass the
  // stale clean L2 lines left by phase-A zeroing (phase-B RMWs hit fabric).
  {
    const unsigned long long* acc8 = (const unsigned long long*)accum;
    float4* out4 = (float4*)out;
    for (int i = gid; i < NZ4; i += NTHR) {
      unsigned long long bits = __hip_atomic_load(acc8 + i, __ATOMIC_RELAXED,
                                                  __HIP_MEMORY_SCOPE_AGENT);
      union { unsigned long long u; half4t h; } cv;
      cv.u = bits;
      out4[i] = make_float4((float)cv.h[0], (float)cv.h[1],
                            (float)cv.h[2], (float)cv.h[3]);
    }
  }
}

extern "C" void kernel_launch(void* const* d_in, const int* in_sizes, int n_in,
                              void* d_out, int out_size, void* d_ws, size_t ws_size,
                              hipStream_t stream) {
  const float* atom  = (const float*)d_in[0];   // (100000, 32) f32
  const float* bondf = (const float*)d_in[1];   // (400000, 16) f32
  const int*   pairs = (const int*)d_in[2];     // (400000, 2) int32
  const float* Kmat  = (const float*)d_in[3];   // (16, 1024) f32
  const float* bias  = (const float*)d_in[4];   // (1024,) f32
  float* out = (float*)d_out;                   // (100000, 32) f32

  char* ws = (char*)d_ws;
  _Float16* atomh = (_Float16*)(ws + OFF_ATOMH);
  _Float16* accum = (_Float16*)(ws + OFF_ACC);
  unsigned* barA  = (unsigned*)(ws + OFF_BARA);
  unsigned* barB  = (unsigned*)(ws + OFF_BARB);
  unsigned* relA  = (unsigned*)(ws + OFF_RELA);
  unsigned* relB  = (unsigned*)(ws + OFF_RELB);

  edge_all<<<NBLK, 256, 0, stream>>>(atom, bondf, pairs, Kmat, bias, out,
                                     atomh, accum, barA, barB, relA, relB);
}

// Round 13
// 125.391 us; speedup vs baseline: 1.3450x; 1.3450x over previous
//
#include <hip/hip_runtime.h>
#include <hip/hip_fp16.h>

// EdgeNetwork: 3 dispatches (PROVEN R10 structure), minimum-traffic prep.
//   k_prep: zero f16 accum ONLY (atom conversion dropped -- atom streamed
//     f32 in edge and converted at use; both paths are L3-served, and the
//     19.2MB conversion pass was pure overhead).
//   edge_fused: full-row waves, MFMA (h0 W-half in regs, h1 in LDS), bond
//     f32-streamed, atom f32-gathered (raw float4v staged, cvt at compute);
//     epilogue = one pk-f16 atomic instruction per edge's 64B accum row.
//   k_fin: accum f16 -> out f32.
//
// Journal:
// R0: hipLaunchCooperativeKernel silently no-ops under graph capture. NEVER.
// R1: occupancy x2 -> neutral/negative in atomic-wall regime.
// R3: dst-sort cut touches 3x but extra dispatches ate the win.
// R4: launch_bounds(256,4) -> VGPR squeeze -> scratch spills. Keep (256,3).
// R5: pk_add_f16 halved atomic DWORDS, time unchanged -> wall = atomic
//     SECTOR-TOUCHES at the coherence point (~14.5G/s). 400k = ~28us floor.
// R6: full-row waves, 1 pk-instr per edge-row: 800k->400k touches. 128.2us.
//     Harness re-poisons the FULL 256MB ws every iteration (43us, fixed).
// R8-R12: megakernel arc. R11's per-block fence fix recovered 160us (fence
//     storms real), but 3 different barrier designs all leave edge_all at
//     ~97-101us vs 3-dispatch kernel-sum ~46us -> structural. DEAD, final.
//     Overhead re-fit: ~25-30us FIXED per iteration + only ~4us/dispatch.
// R10: 3-dispatch minimal prep = 124.1us BEST.
// R13 (this): R10 + zero-only prep + direct f32 atom gather (stage raw
//     float4v pair, cvt at use -- identical rounding, loads stay in flight).

typedef _Float16 half8 __attribute__((ext_vector_type(8)));
typedef _Float16 half4t __attribute__((ext_vector_type(4)));
typedef float float4v __attribute__((ext_vector_type(4)));

constexpr int NA = 100000;
constexpr int E  = 400000;
constexpr int GRP   = E / 16;          // 25000 16-edge groups
constexpr int NBLK  = 768;             // 3 blocks/CU (proven spill-free)
constexpr int NWAVE = NBLK * 4;        // 3072 persistent waves

// ---- workspace layout (bytes) ----
constexpr size_t OFF_ACC = 0;          // f16[NA*32]  6.4 MB

constexpr int NZ4 = NA * 32 / 4;       // accum zero, half4t units (800k)

constexpr int WSTRIDE = 80;            // LDS bytes per W n-row

// ---- k_prep: zero f16 accum only ----
__global__ void k_prep(half4t* __restrict__ accz) {
  int i = blockIdx.x * 256 + threadIdx.x;
  if (i < NZ4) {
    half4t z = { (_Float16)0.f, (_Float16)0.f, (_Float16)0.f, (_Float16)0.f };
    accz[i] = z;
  }
}

static __device__ inline half8 splat8(_Float16 v) {
  half8 r = {v, v, v, v, v, v, v, v};
  return r;
}

// ---- edge_fused: full-row MFMA + one-pk-instruction-per-row scatter ----
__global__ __launch_bounds__(256, 3)
void edge_fused(const float* __restrict__ atom,
                const float* __restrict__ bondf,
                const int* __restrict__ pairs,
                const float* __restrict__ Kmat,
                const float* __restrict__ bias,
                _Float16* __restrict__ accum)
{
  __shared__ __attribute__((aligned(16))) char wl[17 * 16 * WSTRIDE];

  const int tid  = threadIdx.x;
  const int lane = tid & 63;
  const int wid  = blockIdx.x * 4 + (tid >> 6);
  const int q    = lane >> 4;
  const int el   = lane & 15;
  const int j0   = q * 8;

  // LDS: h1 half of W (cols 16..31) + bias row, f16.
  for (int i4 = tid; i4 < 17 * 16 * 32 / 4; i4 += 256) {
    const int i   = i4 * 4;
    const int s   = i >> 9;
    const int r   = i & 511;
    const int n16 = r >> 5;
    const int j   = r & 31;
    const float* src = (s < 16) ? (Kmat + s * 1024 + (n16 + 16) * 32 + j)
                                : (bias + (n16 + 16) * 32 + j);
    float4 v = *(const float4*)src;
    half4t hh = { (_Float16)v.x, (_Float16)v.y, (_Float16)v.z, (_Float16)v.w };
    *(half4t*)(wl + (s * 16 + n16) * WSTRIDE + j * 2) = hh;
  }

  // h0 W-half (cols 0..15) register-resident (proven Wr layout).
  half8 Wr[17];
  #pragma unroll
  for (int s = 0; s < 17; ++s) {
    const float* src = (s < 16) ? (Kmat + s * 1024 + el * 32 + j0)
                                : (bias + el * 32 + j0);
    half8 w;
    #pragma unroll
    for (int j = 0; j < 8; ++j) w[j] = (_Float16)src[j];
    Wr[s] = w;
  }

  __syncthreads();

  const int2* pairs2 = (const int2*)pairs;
  const char* wb = wl + el * WSTRIDE + q * 16;   // h1 frag base (n = el+16)

  auto ldpv = [&](int g) -> int2 {
    const int gc = g < GRP ? g : GRP - 1;        // clamp: loads stay valid
    int2 v = make_int2(0, 0);
    if (lane < 16) v = pairs2[gc * 16 + lane];
    return v;
  };

  // ---- Pipeline prologue.
  int2 pv0 = ldpv(wid);
  int2 pv1 = ldpv(wid + NWAVE);

  float4v nf0_c, nf1_c;                 // raw f32 atom row (converted at use)
  float4v c0_c, c1_c, c2_c, c3_c;       // raw f32 bond row
  {
    const int a = __shfl(pv0.y, el);
    const float4v* ap = (const float4v*)(atom + (size_t)a * 32 + j0);
    nf0_c = ap[0]; nf1_c = ap[1];
    const float4v* br = (const float4v*)(bondf + (size_t)(wid * 16 + el) * 16);
    c0_c = br[0]; c1_c = br[1]; c2_c = br[2]; c3_c = br[3];
  }

  for (int g = wid; g < GRP; g += NWAVE) {
    const int gn = g + NWAVE;

    // ---- Stage next group (raw loads in flight across this group's compute).
    float4v nf0_n, nf1_n, c0_n, c1_n, c2_n, c3_n;
    {
      const int a = __shfl(pv1.y, el);
      const float4v* ap = (const float4v*)(atom + (size_t)a * 32 + j0);
      nf0_n = ap[0]; nf1_n = ap[1];
      const int gc = gn < GRP ? gn : GRP - 1;
      const float4v* br = (const float4v*)(bondf + (size_t)(gc * 16 + el) * 16);
      c0_n = br[0]; c1_n = br[1]; c2_n = br[2]; c3_n = br[3];
    }
    const int2 pv2 = ldpv(gn + NWAVE);

    // Convert this group's atom row f32 -> f16 (same rounding as pre-convert).
    half8 nb_c;
    #pragma unroll
    for (int j = 0; j < 4; ++j) {
      nb_c[j]     = (_Float16)nf0_c[j];
      nb_c[4 + j] = (_Float16)nf1_c[j];
    }

    // Opaque zero (SGPR) so loop-invariant LDS reads are not hoisted.
    int zz;
    asm volatile("s_mov_b32 %0, 0" : "=s"(zz));
    const char* wbz = wb + zz;

    // ---- Compute: 16 edges x 32 cols.
    float4v a0 = {0.f, 0.f, 0.f, 0.f};
    float4v a1 = {0.f, 0.f, 0.f, 0.f};
    #pragma unroll
    for (int s = 0; s < 16; ++s) {
      const float scf = (s < 4) ? c0_c[s] : (s < 8) ? c1_c[s - 4]
                       : (s < 12) ? c2_c[s - 8] : c3_c[s - 12];
      const half8 af = nb_c * splat8((_Float16)scf);
      const half8 w1 = *(const half8*)(wbz + s * 16 * WSTRIDE);
      a0 = __builtin_amdgcn_mfma_f32_16x16x32_f16(af, Wr[s], a0, 0, 0, 0);
      a1 = __builtin_amdgcn_mfma_f32_16x16x32_f16(af, w1,    a1, 0, 0, 0);
    }
    {
      const half8 w1 = *(const half8*)(wbz + 16 * 16 * WSTRIDE);
      a0 = __builtin_amdgcn_mfma_f32_16x16x32_f16(nb_c, Wr[16], a0, 0, 0, 0);
      a1 = __builtin_amdgcn_mfma_f32_16x16x32_f16(nb_c, w1,     a1, 0, 0, 0);
    }

    // ---- Epilogue: one pk-atomic instruction per 4 edge-rows (full 64B row).
    const bool ev = !(el & 1);
    #pragma unroll
    for (int r = 0; r < 4; ++r) {
      const int   d  = __shfl(pv0.x, q * 4 + r);
      const float v0 = a0[r], v1 = a1[r];
      const float p0 = __shfl_xor(v0, 1);
      const float p1 = __shfl_xor(v1, 1);
      union { _Float16 f[2]; __half2 h; } u;
      u.f[0] = ev ? (_Float16)v0 : (_Float16)p1;
      u.f[1] = ev ? (_Float16)p0 : (_Float16)v1;
      const int col = ev ? el : (15 + el);
      unsafeAtomicAdd(reinterpret_cast<__half2*>(
                          accum + (size_t)d * 32 + col), u.h);
    }

    // ---- Rotate pipeline registers.
    pv0 = pv1; pv1 = pv2;
    nf0_c = nf0_n; nf1_c = nf1_n;
    c0_c = c0_n; c1_c = c1_n; c2_c = c2_n; c3_c = c3_n;
  }
}

// ---- k_fin: accum f16 -> out f32 (full overwrite) ----
__global__ void k_fin(const half4t* __restrict__ acc4,
                      float4* __restrict__ out4) {
  int i = blockIdx.x * 256 + threadIdx.x;
  if (i >= NZ4) return;
  half4t v = acc4[i];
  out4[i] = make_float4((float)v[0], (float)v[1], (float)v[2], (float)v[3]);
}

extern "C" void kernel_launch(void* const* d_in, const int* in_sizes, int n_in,
                              void* d_out, int out_size, void* d_ws, size_t ws_size,
                              hipStream_t stream) {
  const float* atom  = (const float*)d_in[0];   // (100000, 32) f32
  const float* bondf = (const float*)d_in[1];   // (400000, 16) f32
  const int*   pairs = (const int*)d_in[2];     // (400000, 2) int32
  const float* Kmat  = (const float*)d_in[3];   // (16, 1024) f32
  const float* bias  = (const float*)d_in[4];   // (1024,) f32
  float* out = (float*)d_out;                   // (100000, 32) f32

  char* ws = (char*)d_ws;
  _Float16* accum = (_Float16*)(ws + OFF_ACC);

  k_prep<<<(NZ4 + 255) / 256, 256, 0, stream>>>((half4t*)accum);
  edge_fused<<<NBLK, 256, 0, stream>>>(atom, bondf, pairs, Kmat, bias, accum);
  k_fin<<<(NZ4 + 255) / 256, 256, 0, stream>>>((const half4t*)accum,
                                               (float4*)out);
}